// Round 5
// baseline (403.750 us; speedup 1.0000x reference)
//
#include <hip/hip_runtime.h>

#define BATCH 8
#define NPTS 9225
#define MQ 4096
#define CAP 64
#define GRID 32
#define NCELLS (GRID * GRID)   // 1024, cell = 1/32 = 0.03125 > r = 0.03

__device__ __forceinline__ int cell_of(float x, float y) {
  int cx = (int)(x * (float)GRID);
  int cy = (int)(y * (float)GRID);
  cx = min(max(cx, 0), GRID - 1);
  cy = min(max(cy, 0), GRID - 1);
  return cy * GRID + cx;
}

// One block per batch: LDS histogram -> LDS scan -> scatter (re-reads points:
// no register cache, avoids the R4 spill at 1024 thr / 64-VGPR budget).
// Also zeroes the per-batch done-flags used by search's fused row-splits scan.
__global__ __launch_bounds__(1024) void build_kernel(
    const float* __restrict__ data,
    int* __restrict__ cell_starts,   // [B][NCELLS+1]
    float2* __restrict__ sdata, int* __restrict__ sidx,
    int* __restrict__ done_flags) {  // [B]
  __shared__ int hist[NCELLS];
  __shared__ int cursor[NCELLS];
  const int b = blockIdx.x;
  const int t = threadIdx.x;
  if (t == 0)
    __hip_atomic_store(&done_flags[b], 0, __ATOMIC_RELAXED, __HIP_MEMORY_SCOPE_AGENT);
  hist[t] = 0;
  __syncthreads();

  const float2* dp = (const float2*)data + (size_t)b * NPTS;
  for (int i = t; i < NPTS; i += 1024)
    atomicAdd(&hist[cell_of(dp[i].x, dp[i].y)], 1);
  __syncthreads();

  const int v = hist[t];
  for (int off = 1; off < NCELLS; off <<= 1) {
    const int u = (t >= off) ? hist[t - off] : 0;
    __syncthreads();
    hist[t] += u;
    __syncthreads();
  }
  const int incl = hist[t];
  const int excl = incl - v;
  cursor[t] = excl;
  cell_starts[b * (NCELLS + 1) + t] = excl;
  if (t == NCELLS - 1) cell_starts[b * (NCELLS + 1) + NCELLS] = incl;
  __syncthreads();

  float2* sd = sdata + (size_t)b * NPTS;
  int* si = sidx + (size_t)b * NPTS;
  for (int i = t; i < NPTS; i += 1024) {
    const float2 p = dp[i];   // re-read (L2 hit) instead of register cache
    const int pos = atomicAdd(&cursor[cell_of(p.x, p.y)], 1);
    sd[pos] = p;
    si[pos] = i;
  }
}

// One wave per query (4/block, 8192 blocks). The last block of each batch
// (device-scope done-counter) performs that batch's row-splits scan inline.
__global__ __launch_bounds__(256) void search_kernel(
    const float* __restrict__ queries, const float* __restrict__ radius_p,
    const int* __restrict__ cell_starts, const float2* __restrict__ sdata,
    const int* __restrict__ sidx, int* __restrict__ nbr_idx,
    int* __restrict__ counts, int* __restrict__ done_flags,
    int* __restrict__ row_splits) {
#pragma clang fp contract(off)
  __shared__ int hitbuf[4][CAP];
  __shared__ int partial[256];
  __shared__ int lastflag;
  const int lane = threadIdx.x & 63;
  const int w = threadIdx.x >> 6;
  const int q = blockIdx.x * 4 + w;     // grid sized exactly: no early-out
  const int b = q >> 12;                // MQ = 4096
  const float r = radius_p[0];
  const float r2 = r * r;
  const float2 qv = ((const float2*)queries)[q];
  const float qx = qv.x, qy = qv.y;
  const float qn = qx * qx + qy * qy;   // mul,mul,add — no fma (matches np)

  const int cx = min(max((int)(qx * (float)GRID), 0), GRID - 1);
  const int cy = min(max((int)(qy * (float)GRID), 0), GRID - 1);
  const int x0 = max(cx - 1, 0), x1 = min(cx + 1, GRID - 1);
  const int y0 = max(cy - 1, 0), y1 = min(cy + 1, GRID - 1);

  const int csbase = b * (NCELLS + 1);
  int rstart[3], rlen[3];
  int nr = 0;
  for (int y = y0; y <= y1; ++y) {
    const int s0 = cell_starts[csbase + y * GRID + x0];
    const int s1 = cell_starts[csbase + y * GRID + x1 + 1];
    rstart[nr] = s0;
    rlen[nr] = s1 - s0;
    ++nr;
  }
  for (int k = nr; k < 3; ++k) { rstart[k] = 0; rlen[k] = 0; }
  const int L0 = rlen[0];
  const int L01 = L0 + rlen[1];
  const int T = L01 + rlen[2];

  const unsigned long long below = (1ull << lane) - 1ull;
  const float2* sd = sdata + (size_t)b * NPTS;
  const int* si = sidx + (size_t)b * NPTS;
  int h = 0;

  for (int base = 0; base < T; base += 64) {
    const int p = base + lane;
    const bool act = (p < T);
    int i;
    if (p < L0)        i = rstart[0] + p;
    else if (p < L01)  i = rstart[1] + (p - L0);
    else               i = rstart[2] + (p - L01);
    if (!act) i = 0;  // safe address
    const float2 pt = sd[i];
    const int id = si[i];
    const float dx = pt.x, dy = pt.y;
    const float dn = dx * dx + dy * dy;            // mul,mul,add — no fma
    const float cross = qx * dx + qy * dy;         // mul,mul,add — no fma
    const float s = (qn + dn) - 2.0f * cross;      // matches np op order
    const bool in = act && (s <= r2);
    const unsigned long long mask = __ballot(in);
    if (mask != 0ull) {
      if (in) {
        const int pos = h + __popcll(mask & below);
        if (pos < CAP) hitbuf[w][pos] = id;
      }
      h += __popcll(mask);
    }
  }

  // gather (same-wave LDS RAW is in-order)
  int v = (lane < h && lane < CAP) ? hitbuf[w][lane] : 0x7fffffff;

  // bitonic sort: k=2..32 sorts each 32-half (low asc, high = all-MAX)
#pragma unroll
  for (int k = 2; k <= 32; k <<= 1) {
#pragma unroll
    for (int j = k >> 1; j >= 1; j >>= 1) {
      const int other = __shfl_xor(v, j, 64);
      const bool keep_min = (((lane & k) == 0) == ((lane & j) == 0));
      v = keep_min ? min(v, other) : max(v, other);
    }
  }
  if (h > 32) {  // final 64-merge only if hits spill past lane 31
#pragma unroll
    for (int j = 32; j >= 1; j >>= 1) {
      const int other = __shfl_xor(v, j, 64);
      const bool keep_min = ((lane & j) == 0);
      v = keep_min ? min(v, other) : max(v, other);
    }
  }

  nbr_idx[(size_t)q * CAP + lane] = (v == 0x7fffffff) ? -1 : v;
  if (lane == 0)
    __hip_atomic_store(&counts[q], h, __ATOMIC_RELAXED, __HIP_MEMORY_SCOPE_AGENT);

  // ---- fused per-batch row-splits scan (last block of the batch) ----
  __syncthreads();  // all 4 waves' count stores issued
  if (threadIdx.x == 0) {
    __threadfence();  // release: counts visible device-wide before increment
    const int old = __hip_atomic_fetch_add(&done_flags[b], 1,
                                           __ATOMIC_ACQ_REL, __HIP_MEMORY_SCOPE_AGENT);
    lastflag = (old == (MQ / 4) - 1);  // 1024 blocks per batch
  }
  __syncthreads();
  if (lastflag) {
    __threadfence();  // acquire: see all other blocks' count stores
    const int t = threadIdx.x;
    const int PER = MQ / 256;  // 16
    const int* c = counts + b * MQ;
    int local[PER];
    int sum = 0;
#pragma unroll
    for (int k = 0; k < PER; ++k) {
      local[k] = __hip_atomic_load(&c[t * PER + k], __ATOMIC_RELAXED,
                                   __HIP_MEMORY_SCOPE_AGENT);
      sum += local[k];
    }
    partial[t] = sum;
    __syncthreads();
    for (int off = 1; off < 256; off <<= 1) {
      const int u = (t >= off) ? partial[t - off] : 0;
      __syncthreads();
      partial[t] += u;
      __syncthreads();
    }
    const int excl = (t == 0) ? 0 : partial[t - 1];
    int* rs = row_splits + b * (MQ + 1);
    if (t == 0) rs[0] = 0;
    int run = excl;
#pragma unroll
    for (int k = 0; k < PER; ++k) { run += local[k]; rs[t * PER + k + 1] = run; }
  }
}

extern "C" void kernel_launch(void* const* d_in, const int* in_sizes, int n_in,
                              void* d_out, int out_size, void* d_ws, size_t ws_size,
                              hipStream_t stream) {
  const float* data    = (const float*)d_in[0];
  const float* queries = (const float*)d_in[1];
  const float* radius  = (const float*)d_in[2];
  int* out        = (int*)d_out;
  int* nbr_idx    = out;                       // BATCH*MQ*CAP
  int* row_splits = out + BATCH * MQ * CAP;    // BATCH*(MQ+1)

  // workspace layout (ints)
  int* counts      = (int*)d_ws;                         // 32768
  int* cell_starts = counts + BATCH * MQ;                // 8200
  int* done_flags  = cell_starts + BATCH * (NCELLS + 1); // 8
  int* sidx        = done_flags + BATCH;                 // 73800
  float2* sdata    = (float2*)(sidx + BATCH * NPTS + 2); // pad to 8B alignment

  hipLaunchKernelGGL(build_kernel, dim3(BATCH), dim3(1024), 0, stream,
                     data, cell_starts, sdata, sidx, done_flags);
  hipLaunchKernelGGL(search_kernel, dim3(BATCH * MQ / 4), dim3(256), 0, stream,
                     queries, radius, cell_starts, sdata, sidx, nbr_idx,
                     counts, done_flags, row_splits);
}

// Round 6
// 95.269 us; speedup vs baseline: 4.2380x; 4.2380x over previous
//
#include <hip/hip_runtime.h>

#define BATCH 8
#define NPTS 9225
#define MQ 4096
#define CAP 64
#define GRID 32
#define NCELLS (GRID * GRID)   // 1024, cell = 1/32 = 0.03125 > r = 0.03

__device__ __forceinline__ int cell_of(float x, float y) {
  int cx = (int)(x * (float)GRID);
  int cy = (int)(y * (float)GRID);
  cx = min(max(cx, 0), GRID - 1);
  cy = min(max(cy, 0), GRID - 1);
  return cy * GRID + cx;
}

// One block per batch: LDS histogram -> LDS scan -> scatter. No register
// point-cache (R4's spill); re-reads data from L2 instead.
__global__ __launch_bounds__(1024) void build_kernel(
    const float* __restrict__ data,
    int* __restrict__ cell_starts,   // [B][NCELLS+1]
    float2* __restrict__ sdata, int* __restrict__ sidx) {
  __shared__ int hist[NCELLS];
  __shared__ int cursor[NCELLS];
  const int b = blockIdx.x;
  const int t = threadIdx.x;
  hist[t] = 0;
  __syncthreads();

  const float2* dp = (const float2*)data + (size_t)b * NPTS;
  for (int i = t; i < NPTS; i += 1024)
    atomicAdd(&hist[cell_of(dp[i].x, dp[i].y)], 1);
  __syncthreads();

  const int v = hist[t];
  for (int off = 1; off < NCELLS; off <<= 1) {
    const int u = (t >= off) ? hist[t - off] : 0;
    __syncthreads();
    hist[t] += u;
    __syncthreads();
  }
  const int incl = hist[t];
  const int excl = incl - v;
  cursor[t] = excl;
  cell_starts[b * (NCELLS + 1) + t] = excl;
  if (t == NCELLS - 1) cell_starts[b * (NCELLS + 1) + NCELLS] = incl;
  __syncthreads();

  float2* sd = sdata + (size_t)b * NPTS;
  int* si = sidx + (size_t)b * NPTS;
  for (int i = t; i < NPTS; i += 1024) {
    const float2 p = dp[i];   // re-read (L2 hit)
    const int pos = atomicAdd(&cursor[cell_of(p.x, p.y)], 1);
    sd[pos] = p;
    si[pos] = i;
  }
}

// One wave per query; 3 cell-rows concatenated into one lane-mapped stream.
// NO cross-workgroup handshakes (R5 lesson: each agent fence = L2 flush).
__global__ __launch_bounds__(256) void search_kernel(
    const float* __restrict__ queries, const float* __restrict__ radius_p,
    const int* __restrict__ cell_starts, const float2* __restrict__ sdata,
    const int* __restrict__ sidx, int* __restrict__ nbr_idx,
    int* __restrict__ counts) {
#pragma clang fp contract(off)
  __shared__ int hitbuf[4][CAP];
  const int lane = threadIdx.x & 63;
  const int w = threadIdx.x >> 6;
  const int q = blockIdx.x * 4 + w;     // grid sized exactly
  const int b = q >> 12;                // MQ = 4096
  const float r = radius_p[0];
  const float r2 = r * r;
  const float2 qv = ((const float2*)queries)[q];
  const float qx = qv.x, qy = qv.y;
  const float qn = qx * qx + qy * qy;   // mul,mul,add — no fma (matches np)

  const int cx = min(max((int)(qx * (float)GRID), 0), GRID - 1);
  const int cy = min(max((int)(qy * (float)GRID), 0), GRID - 1);
  const int x0 = max(cx - 1, 0), x1 = min(cx + 1, GRID - 1);
  const int y0 = max(cy - 1, 0), y1 = min(cy + 1, GRID - 1);

  const int csbase = b * (NCELLS + 1);
  int rstart[3], rlen[3];
  int nr = 0;
  for (int y = y0; y <= y1; ++y) {
    const int s0 = cell_starts[csbase + y * GRID + x0];
    const int s1 = cell_starts[csbase + y * GRID + x1 + 1];
    rstart[nr] = s0;
    rlen[nr] = s1 - s0;
    ++nr;
  }
  for (int k = nr; k < 3; ++k) { rstart[k] = 0; rlen[k] = 0; }
  const int L0 = rlen[0];
  const int L01 = L0 + rlen[1];
  const int T = L01 + rlen[2];

  const unsigned long long below = (1ull << lane) - 1ull;
  const float2* sd = sdata + (size_t)b * NPTS;
  const int* si = sidx + (size_t)b * NPTS;
  int h = 0;

  for (int base = 0; base < T; base += 64) {
    const int p = base + lane;
    const bool act = (p < T);
    int i;
    if (p < L0)        i = rstart[0] + p;
    else if (p < L01)  i = rstart[1] + (p - L0);
    else               i = rstart[2] + (p - L01);
    if (!act) i = 0;  // safe address
    const float2 pt = sd[i];
    const int id = si[i];
    const float dx = pt.x, dy = pt.y;
    const float dn = dx * dx + dy * dy;            // mul,mul,add — no fma
    const float cross = qx * dx + qy * dy;         // mul,mul,add — no fma
    const float s = (qn + dn) - 2.0f * cross;      // matches np op order
    const bool in = act && (s <= r2);
    const unsigned long long mask = __ballot(in);
    if (mask != 0ull) {
      if (in) {
        const int pos = h + __popcll(mask & below);
        if (pos < CAP) hitbuf[w][pos] = id;
      }
      h += __popcll(mask);
    }
  }

  // gather (same-wave LDS RAW is in-order)
  int v = (lane < h && lane < CAP) ? hitbuf[w][lane] : 0x7fffffff;

  // bitonic sort: k=2..32 sorts each 32-half (high half = all-MAX)
#pragma unroll
  for (int k = 2; k <= 32; k <<= 1) {
#pragma unroll
    for (int j = k >> 1; j >= 1; j >>= 1) {
      const int other = __shfl_xor(v, j, 64);
      const bool keep_min = (((lane & k) == 0) == ((lane & j) == 0));
      v = keep_min ? min(v, other) : max(v, other);
    }
  }
  if (h > 32) {  // final 64-merge only if hits spill past lane 31
#pragma unroll
    for (int j = 32; j >= 1; j >>= 1) {
      const int other = __shfl_xor(v, j, 64);
      const bool keep_min = ((lane & j) == 0);
      v = keep_min ? min(v, other) : max(v, other);
    }
  }

  nbr_idx[(size_t)q * CAP + lane] = (v == 0x7fffffff) ? -1 : v;
  if (lane == 0) counts[q] = h;
}

// Per-batch exclusive scan of 4096 counts -> row_splits[b][0..4096]
__global__ __launch_bounds__(256) void scan_kernel(const int* __restrict__ counts,
                                                   int* __restrict__ row_splits) {
  const int b = blockIdx.x;
  const int t = threadIdx.x;
  const int PER = MQ / 256;  // 16
  __shared__ int partial[256];
  const int* c = counts + b * MQ;
  int local[PER];
  int sum = 0;
#pragma unroll
  for (int k = 0; k < PER; ++k) { local[k] = c[t * PER + k]; sum += local[k]; }
  partial[t] = sum;
  __syncthreads();
  for (int off = 1; off < 256; off <<= 1) {
    int u = (t >= off) ? partial[t - off] : 0;
    __syncthreads();
    partial[t] += u;
    __syncthreads();
  }
  const int excl = (t == 0) ? 0 : partial[t - 1];
  int* rs = row_splits + b * (MQ + 1);
  if (t == 0) rs[0] = 0;
  int run = excl;
#pragma unroll
  for (int k = 0; k < PER; ++k) { run += local[k]; rs[t * PER + k + 1] = run; }
}

extern "C" void kernel_launch(void* const* d_in, const int* in_sizes, int n_in,
                              void* d_out, int out_size, void* d_ws, size_t ws_size,
                              hipStream_t stream) {
  const float* data    = (const float*)d_in[0];
  const float* queries = (const float*)d_in[1];
  const float* radius  = (const float*)d_in[2];
  int* out        = (int*)d_out;
  int* nbr_idx    = out;                       // BATCH*MQ*CAP
  int* row_splits = out + BATCH * MQ * CAP;    // BATCH*(MQ+1)

  // workspace layout (ints)
  int* counts      = (int*)d_ws;                         // 32768
  int* cell_starts = counts + BATCH * MQ;                // 8200
  int* sidx        = cell_starts + BATCH * (NCELLS + 1); // 73800
  float2* sdata    = (float2*)(sidx + BATCH * NPTS + 2); // 8B-aligned

  hipLaunchKernelGGL(build_kernel, dim3(BATCH), dim3(1024), 0, stream,
                     data, cell_starts, sdata, sidx);
  hipLaunchKernelGGL(search_kernel, dim3(BATCH * MQ / 4), dim3(256), 0, stream,
                     queries, radius, cell_starts, sdata, sidx, nbr_idx, counts);
  hipLaunchKernelGGL(scan_kernel, dim3(BATCH), dim3(256), 0, stream,
                     counts, row_splits);
}

// Round 7
// 91.288 us; speedup vs baseline: 4.4228x; 1.0436x over previous
//
#include <hip/hip_runtime.h>

#define BATCH 8
#define NPTS 9225
#define MQ 4096
#define CAP 64
#define GRID 64
#define NCELLS (GRID * GRID)   // 4096; window = cx±2, cy±2 (5x5 cells)
// coverage margin: query at qx covers [ (cx-2)/64, (cx+3)/64 ) => >= 2/64 =
// 0.03125 each side vs r = 0.03 (+fp32-expansion slack ~2e-6). Same 0.00125
// margin as the old 3x3/32 window, but ~56 candidates instead of ~81.

__device__ __forceinline__ int cell_of(float x, float y) {
  int cx = (int)(x * (float)GRID);
  int cy = (int)(y * (float)GRID);
  cx = min(max(cx, 0), GRID - 1);
  cy = min(max(cy, 0), GRID - 1);
  return cy * GRID + cx;
}

// One block per batch: LDS histogram -> shfl-based scan (4 barriers total,
// was ~22) -> scatter of merged 16B records (x, y, idx_bits, 0).
__global__ __launch_bounds__(1024) void build_kernel(
    const float* __restrict__ data,
    int* __restrict__ cell_starts,   // [B][NCELLS+1]
    float4* __restrict__ recs) {     // [B][NPTS]
  __shared__ int hist[NCELLS];
  __shared__ int cursor[NCELLS];
  __shared__ int wavesum[16];
  const int b = blockIdx.x;
  const int t = threadIdx.x;
#pragma unroll
  for (int k = 0; k < NCELLS / 1024; ++k) hist[t + k * 1024] = 0;
  __syncthreads();

  const float2* dp = (const float2*)data + (size_t)b * NPTS;
  for (int i = t; i < NPTS; i += 1024)
    atomicAdd(&hist[cell_of(dp[i].x, dp[i].y)], 1);
  __syncthreads();

  // scan: thread t owns cells [4t, 4t+4)
  const int c0 = hist[4 * t + 0], c1 = hist[4 * t + 1];
  const int c2 = hist[4 * t + 2], c3 = hist[4 * t + 3];
  const int s = c0 + c1 + c2 + c3;
  const int lane = t & 63, wid = t >> 6;
  int v = s;
#pragma unroll
  for (int off = 1; off < 64; off <<= 1) {
    const int u = __shfl_up(v, off, 64);
    if (lane >= off) v += u;
  }
  if (lane == 63) wavesum[wid] = v;
  __syncthreads();
  int woff = 0;
  for (int k = 0; k < wid; ++k) woff += wavesum[k];
  int e = woff + v - s;  // exclusive prefix of cell 4t
  int* cs = cell_starts + b * (NCELLS + 1);
  cs[4 * t + 0] = e; cursor[4 * t + 0] = e; e += c0;
  cs[4 * t + 1] = e; cursor[4 * t + 1] = e; e += c1;
  cs[4 * t + 2] = e; cursor[4 * t + 2] = e; e += c2;
  cs[4 * t + 3] = e; cursor[4 * t + 3] = e; e += c3;
  if (t == 1023) cs[NCELLS] = e;  // == NPTS
  __syncthreads();

  float4* rb = recs + (size_t)b * NPTS;
  for (int i = t; i < NPTS; i += 1024) {
    const float2 p = dp[i];  // re-read (L2 hit); register cache spilled in R4
    const int pos = atomicAdd(&cursor[cell_of(p.x, p.y)], 1);
    rb[pos] = make_float4(p.x, p.y, __int_as_float(i), 0.0f);
  }
}

// One wave per query; 5 cell-rows concatenated into one lane-mapped stream,
// one 16B record load per candidate. No cross-workgroup handshakes (R5:
// every agent fence = L2 flush).
__global__ __launch_bounds__(256) void search_kernel(
    const float* __restrict__ queries, const float* __restrict__ radius_p,
    const int* __restrict__ cell_starts, const float4* __restrict__ recs,
    int* __restrict__ nbr_idx, int* __restrict__ counts) {
#pragma clang fp contract(off)
  __shared__ int hitbuf[4][CAP];
  const int lane = threadIdx.x & 63;
  const int w = threadIdx.x >> 6;
  const int q = blockIdx.x * 4 + w;     // grid sized exactly
  const int b = q >> 12;                // MQ = 4096
  const float r = radius_p[0];
  const float r2 = r * r;
  const float2 qv = ((const float2*)queries)[q];
  const float qx = qv.x, qy = qv.y;
  const float qn = qx * qx + qy * qy;   // mul,mul,add — no fma (matches np)

  const int cx = min(max((int)(qx * (float)GRID), 0), GRID - 1);
  const int cy = min(max((int)(qy * (float)GRID), 0), GRID - 1);
  const int x0 = max(cx - 2, 0), x1 = min(cx + 2, GRID - 1);
  const int y0 = max(cy - 2, 0), y1 = min(cy + 2, GRID - 1);

  const int csbase = b * (NCELLS + 1);
  int rstart[5], rlen[5];
  int nr = 0;
  for (int y = y0; y <= y1; ++y) {      // wave-uniform trip count (3..5)
    const int s0 = cell_starts[csbase + y * GRID + x0];
    const int s1 = cell_starts[csbase + y * GRID + x1 + 1];
    rstart[nr] = s0;
    rlen[nr] = s1 - s0;
    ++nr;
  }
  for (int k = nr; k < 5; ++k) { rstart[k] = 0; rlen[k] = 0; }
  const int L0 = rlen[0];
  const int L1 = L0 + rlen[1];
  const int L2 = L1 + rlen[2];
  const int L3 = L2 + rlen[3];
  const int T = L3 + rlen[4];

  const unsigned long long below = (1ull << lane) - 1ull;
  const float4* rb = recs + (size_t)b * NPTS;
  int h = 0;

  for (int base = 0; base < T; base += 64) {
    const int p = base + lane;
    const bool act = (p < T);
    int i;
    if (p < L0)      i = rstart[0] + p;
    else if (p < L1) i = rstart[1] + (p - L0);
    else if (p < L2) i = rstart[2] + (p - L1);
    else if (p < L3) i = rstart[3] + (p - L2);
    else             i = rstart[4] + (p - L3);
    if (!act) i = 0;  // safe address
    const float4 rec = rb[i];
    const float dx = rec.x, dy = rec.y;
    const int id = __float_as_int(rec.z);
    const float dn = dx * dx + dy * dy;            // mul,mul,add — no fma
    const float cross = qx * dx + qy * dy;         // mul,mul,add — no fma
    const float s = (qn + dn) - 2.0f * cross;      // matches np op order
    const bool in = act && (s <= r2);
    const unsigned long long mask = __ballot(in);
    if (in) {
      const int pos = h + __popcll(mask & below);
      if (pos < CAP) hitbuf[w][pos] = id;
    }
    h += __popcll(mask);
  }

  // gather (same-wave LDS RAW is in-order)
  int v = (lane < h && lane < CAP) ? hitbuf[w][lane] : 0x7fffffff;

  // bitonic sort: k=2..32 sorts each 32-half (high half = all-MAX)
#pragma unroll
  for (int k = 2; k <= 32; k <<= 1) {
#pragma unroll
    for (int j = k >> 1; j >= 1; j >>= 1) {
      const int other = __shfl_xor(v, j, 64);
      const bool keep_min = (((lane & k) == 0) == ((lane & j) == 0));
      v = keep_min ? min(v, other) : max(v, other);
    }
  }
  if (h > 32) {  // final 64-merge only if hits spill past lane 31
#pragma unroll
    for (int j = 32; j >= 1; j >>= 1) {
      const int other = __shfl_xor(v, j, 64);
      const bool keep_min = ((lane & j) == 0);
      v = keep_min ? min(v, other) : max(v, other);
    }
  }

  nbr_idx[(size_t)q * CAP + lane] = (v == 0x7fffffff) ? -1 : v;
  if (lane == 0) counts[q] = h;
}

// Per-batch exclusive scan of 4096 counts -> row_splits[b][0..4096]
__global__ __launch_bounds__(256) void scan_kernel(const int* __restrict__ counts,
                                                   int* __restrict__ row_splits) {
  const int b = blockIdx.x;
  const int t = threadIdx.x;
  const int PER = MQ / 256;  // 16
  __shared__ int partial[256];
  const int* c = counts + b * MQ;
  int local[PER];
  int sum = 0;
#pragma unroll
  for (int k = 0; k < PER; ++k) { local[k] = c[t * PER + k]; sum += local[k]; }
  partial[t] = sum;
  __syncthreads();
  for (int off = 1; off < 256; off <<= 1) {
    int u = (t >= off) ? partial[t - off] : 0;
    __syncthreads();
    partial[t] += u;
    __syncthreads();
  }
  const int excl = (t == 0) ? 0 : partial[t - 1];
  int* rs = row_splits + b * (MQ + 1);
  if (t == 0) rs[0] = 0;
  int run = excl;
#pragma unroll
  for (int k = 0; k < PER; ++k) { run += local[k]; rs[t * PER + k + 1] = run; }
}

extern "C" void kernel_launch(void* const* d_in, const int* in_sizes, int n_in,
                              void* d_out, int out_size, void* d_ws, size_t ws_size,
                              hipStream_t stream) {
  const float* data    = (const float*)d_in[0];
  const float* queries = (const float*)d_in[1];
  const float* radius  = (const float*)d_in[2];
  int* out        = (int*)d_out;
  int* nbr_idx    = out;                       // BATCH*MQ*CAP
  int* row_splits = out + BATCH * MQ * CAP;    // BATCH*(MQ+1)

  // workspace layout (ints); counts+cell_starts = 65544 ints = 262176 B,
  // divisible by 16 -> recs is 16B-aligned.
  int* counts      = (int*)d_ws;                         // 32768
  int* cell_starts = counts + BATCH * MQ;                // 8*4097 = 32776
  float4* recs     = (float4*)(cell_starts + BATCH * (NCELLS + 1));

  hipLaunchKernelGGL(build_kernel, dim3(BATCH), dim3(1024), 0, stream,
                     data, cell_starts, recs);
  hipLaunchKernelGGL(search_kernel, dim3(BATCH * MQ / 4), dim3(256), 0, stream,
                     queries, radius, cell_starts, recs, nbr_idx, counts);
  hipLaunchKernelGGL(scan_kernel, dim3(BATCH), dim3(256), 0, stream,
                     counts, row_splits);
}